// Round 2
// baseline (57315.533 us; speedup 1.0000x reference)
//
#include <hip/hip_runtime.h>

typedef unsigned short u16;
typedef unsigned int   u32;

#define SCALE_F 0.08838834764831845f  // 1/sqrt(128)

// ---------- ws layout (float offsets) ----------
#define O_QUERY  0           // 512
#define O_NQ     512         // 512
#define O_WK     1024        // 2048
#define O_KB     3072        // 4  (flag at int ofs 3080, nan counter at 3081)
#define O_FLAG   3080
#define O_AV     4096        // 64*4*512 = 131072
#define O_HEAD   135168      // 64*512  = 32768
#define O_CTXT   167936      // 512*64  = 32768  (contextT[i][b])
#define O_EMBG   200704      // 4096*34 = 139264
#define O_CTXG   339968      // 4096*64 = 262144
#define O_CTXP1  602112      // 512*64  = 32768
#define O_H0T    634880      // 2 * 1024*64 = 131072
#define O_C0T    765952      // 1024*64 = 65536
#define O_H1T    831488      // 2 * 1024*64 = 131072
#define O_C1T    962560      // 65536
#define O_H2T    1028096     // 2 * 512*64 = 65536
#define O_C2T    1093632     // 32768
#define O_YT     1126400     // 32768
#define O_LABT   1159168     // 255*64 ints = 16320
#define O_CANON  1175552     // canonical bf16 weights start (u16 ofs = 2*O_CANON)
// canonical region ~21.81M u16 = ~43.6 MB; total ws need ~48.5 MB

__device__ __forceinline__ float bfc(u16 x) {
    return __uint_as_float(((u32)x) << 16);
}
__device__ __forceinline__ float2 bfpair(u32 u) {
    return make_float2(__uint_as_float(u << 16), __uint_as_float(u & 0xffff0000u));
}
__device__ __forceinline__ u16 f2bf(float f) {
    u32 u = __float_as_uint(f);
    u += 0x7fffu + ((u >> 16) & 1u);
    return (u16)(u >> 16);
}
__device__ __forceinline__ float sigf(float x) { return 1.0f / (1.0f + __expf(-x)); }
__device__ __forceinline__ float tanh_(float x) { return 2.0f / (1.0f + __expf(-2.0f * x)) - 1.0f; }

__device__ __forceinline__ void fma8(float& acc, uint4 a, const float h[8]) {
    float2 p;
    p = bfpair(a.x); acc = fmaf(h[0], p.x, acc); acc = fmaf(h[1], p.y, acc);
    p = bfpair(a.y); acc = fmaf(h[2], p.x, acc); acc = fmaf(h[3], p.y, acc);
    p = bfpair(a.z); acc = fmaf(h[4], p.x, acc); acc = fmaf(h[5], p.y, acc);
    p = bfpair(a.w); acc = fmaf(h[6], p.x, acc); acc = fmaf(h[7], p.y, acc);
}

// acc_g += sum_k hT[k*64+lane] * W[r_g*ldw + k]   (4 weight rows share the h loads)
__device__ __forceinline__ void dot4(const u16* W, int r0, int r1, int r2, int r3,
                                     int ldw, int K, const float* hT, int lane,
                                     float& a0, float& a1, float& a2, float& a3) {
    const u32* w0 = (const u32*)(W + (size_t)r0 * ldw);
    const u32* w1 = (const u32*)(W + (size_t)r1 * ldw);
    const u32* w2 = (const u32*)(W + (size_t)r2 * ldw);
    const u32* w3 = (const u32*)(W + (size_t)r3 * ldw);
#pragma unroll 2
    for (int k = 0; k < K; k += 8) {
        float h[8];
#pragma unroll
        for (int i = 0; i < 8; i++) h[i] = hT[(k + i) * 64 + lane];
        uint4 b0 = *(const uint4*)(w0 + (k >> 1));
        uint4 b1 = *(const uint4*)(w1 + (k >> 1));
        uint4 b2 = *(const uint4*)(w2 + (k >> 1));
        uint4 b3 = *(const uint4*)(w3 + (k >> 1));
        fma8(a0, b0, h); fma8(a1, b1, h); fma8(a2, b2, h); fma8(a3, b3, h);
    }
}

// ---------------- dtype detect + canonicalize ----------------

// Scan first 65536 u16 of a float tensor (>=64K u16 in either dtype).
// True bf16 weights (sigma 0.05): all |x| small. fp32 bits read as bf16:
// thousands of huge/NaN patterns. flag[0]=1 -> bf16, 0 -> fp32. flag[1]=0 (nan ctr).
__global__ __launch_bounds__(256) void las_detect(const u16* w, int* flag) {
    __shared__ int s[256];
    int bad = 0;
    for (int i = threadIdx.x; i < 65536; i += 256) {
        u16 v = w[i];
        if ((v & 0x7F80u) == 0x7F80u) bad++;                  // inf/NaN pattern
        else if (fabsf(bfc(v)) > 1e4f) bad++;                 // absurd magnitude
    }
    s[threadIdx.x] = bad; __syncthreads();
    for (int o = 128; o; o >>= 1) {
        if (threadIdx.x < o) s[threadIdx.x] += s[threadIdx.x + o];
        __syncthreads();
    }
    if (threadIdx.x == 0) { flag[0] = (s[0] == 0) ? 1 : 0; flag[1] = 0; }
}

#define NSEG 32
struct Cvt {
    const void* src[NSEG];
    unsigned ofs[NSEG + 1];   // padded cumulative offsets (u16 units, each 8-aligned)
    unsigned len[NSEG];       // true element counts (all even)
};

__global__ __launch_bounds__(256) void las_convert(Cvt c, const int* flag, u16* dst) {
    int isb = flag[0];
    unsigned total = c.ofs[NSEG] >> 1;   // u16 pairs
    for (unsigned p = blockIdx.x * 256 + threadIdx.x; p < total; p += gridDim.x * 256) {
        unsigned e = p << 1;
        int lo = 0, hi = NSEG;
        while (hi - lo > 1) { int mid = (lo + hi) >> 1; if (c.ofs[mid] <= e) lo = mid; else hi = mid; }
        unsigned local = e - c.ofs[lo];
        u32 out;
        if (local >= c.len[lo]) {
            out = 0;                                          // padding
        } else if (isb) {
            out = ((const u32*)c.src[lo])[local >> 1];        // plain bf16 copy
        } else {
            const float* s = (const float*)c.src[lo];
            u32 a = f2bf(s[local]), b = f2bf(s[local + 1]);
            out = a | (b << 16);
        }
        ((u32*)dst)[p] = out;
    }
}

// ---------------- one-time kernels (all read canonical bf16) ----------------

__global__ __launch_bounds__(256) void las_init(
    const u16* h00, const u16* c00, const u16* h01, const u16* c01,
    const u16* h02, const u16* c02, const int* label,
    float* h0T0, float* c0T, float* h1T0, float* c1T, float* h2T0, float* c2T, int* labT) {
    int idx = blockIdx.x * 256 + threadIdx.x;   // 65536 threads
    int j = idx >> 6, b = idx & 63;
    h0T0[idx] = bfc(h00[j]); c0T[idx] = bfc(c00[j]);
    h1T0[idx] = bfc(h01[j]); c1T[idx] = bfc(c01[j]);
    if (j < 512) { h2T0[idx] = bfc(h02[j]); c2T[idx] = bfc(c02[j]); }
    if (j < 255) { labT[idx] = label[b * 256 + j]; }
}

__global__ __launch_bounds__(256) void las_query(const u16* h02, const u16* W_query,
                                                 const u16* b_query, float* query) {
    int i = blockIdx.x * 256 + threadIdx.x;     // < 512
    float acc = bfc(b_query[i]);
    const u32* wr = (const u32*)(W_query + (size_t)i * 512);
    const u32* hp = (const u32*)h02;
    for (int h = 0; h < 512; h += 8) {
        uint4 wv = *(const uint4*)(wr + (h >> 1));
        uint4 hv = *(const uint4*)(hp + (h >> 1));
        float2 a, c;
        a = bfpair(wv.x); c = bfpair(hv.x); acc = fmaf(a.x, c.x, acc); acc = fmaf(a.y, c.y, acc);
        a = bfpair(wv.y); c = bfpair(hv.y); acc = fmaf(a.x, c.x, acc); acc = fmaf(a.y, c.y, acc);
        a = bfpair(wv.z); c = bfpair(hv.z); acc = fmaf(a.x, c.x, acc); acc = fmaf(a.y, c.y, acc);
        a = bfpair(wv.w); c = bfpair(hv.w); acc = fmaf(a.x, c.x, acc); acc = fmaf(a.y, c.y, acc);
    }
    query[i] = acc;
}

__global__ __launch_bounds__(256) void las_nq(const float* query, const u16* Wq,
                                              const u16* bq, float* nq) {
    int nd = blockIdx.x * 256 + threadIdx.x;    // < 512
    float acc = bfc(bq[nd]);
    const u32* wr = (const u32*)(Wq + (size_t)nd * 512);
    for (int h = 0; h < 512; h += 8) {
        uint4 wv = *(const uint4*)(wr + (h >> 1));
        float2 p;
        p = bfpair(wv.x); acc = fmaf(p.x, query[h + 0], acc); acc = fmaf(p.y, query[h + 1], acc);
        p = bfpair(wv.y); acc = fmaf(p.x, query[h + 2], acc); acc = fmaf(p.y, query[h + 3], acc);
        p = bfpair(wv.z); acc = fmaf(p.x, query[h + 4], acc); acc = fmaf(p.y, query[h + 5], acc);
        p = bfpair(wv.w); acc = fmaf(p.x, query[h + 6], acc); acc = fmaf(p.y, query[h + 7], acc);
    }
    nq[nd] = acc;
}

__global__ __launch_bounds__(256) void las_wk(const float* nq, const u16* Wk, const u16* bk,
                                              float* wk, float* kb) {
    int idx = blockIdx.x * 256 + threadIdx.x;   // < 2048
    int n = idx >> 9, h = idx & 511;
    float acc = 0.0f;
    for (int d = 0; d < 128; d++)
        acc = fmaf(nq[n * 128 + d], bfc(Wk[((size_t)(n * 128 + d)) * 512 + h]), acc);
    wk[idx] = acc;
    if (idx < 4) {
        float kk = 0.0f;
        for (int d = 0; d < 128; d++) kk = fmaf(nq[idx * 128 + d], bfc(bk[idx * 128 + d]), kk);
        kb[idx] = kk;
    }
}

__global__ __launch_bounds__(256) void las_attn(const void* keysv, const void* valuesv,
                                                const int* input_len, const int* flag,
                                                const float* wk, const float* kb, float* av) {
    __shared__ float wk_s[2048];
    __shared__ float kb_s[4];
    __shared__ float sm[4][1024];
    __shared__ float red[256];
    __shared__ float stat[4];
    const u16* keysB = (const u16*)keysv;
    const float* keysF = (const float*)keysv;
    const u16* valB = (const u16*)valuesv;
    const float* valF = (const float*)valuesv;
    int b = blockIdx.x;
    int tid = threadIdx.x;
    int isb = flag[0];
    for (int i = tid; i < 2048; i += 256) wk_s[i] = wk[i];
    if (tid < 4) kb_s[tid] = kb[tid];
    __syncthreads();
    int len = input_len[b];

    // scores for 4 t's x 4 heads per thread
    {
        float acc[4][4];
#pragma unroll
        for (int tl = 0; tl < 4; tl++)
#pragma unroll
            for (int n = 0; n < 4; n++) acc[tl][n] = kb_s[n];
        for (int h = 0; h < 512; h += 8) {
            float kf[4][8];
#pragma unroll
            for (int tl = 0; tl < 4; tl++) {
                int t = tid + 256 * tl;
                size_t base = ((size_t)t * 64 + b) * 512 + h;
                if (isb) {
                    uint4 kv = *(const uint4*)(keysB + base);
                    float2 p;
                    p = bfpair(kv.x); kf[tl][0] = p.x; kf[tl][1] = p.y;
                    p = bfpair(kv.y); kf[tl][2] = p.x; kf[tl][3] = p.y;
                    p = bfpair(kv.z); kf[tl][4] = p.x; kf[tl][5] = p.y;
                    p = bfpair(kv.w); kf[tl][6] = p.x; kf[tl][7] = p.y;
                } else {
                    const float4* kp = (const float4*)(keysF + base);
                    float4 q0 = kp[0], q1 = kp[1];
                    kf[tl][0] = q0.x; kf[tl][1] = q0.y; kf[tl][2] = q0.z; kf[tl][3] = q0.w;
                    kf[tl][4] = q1.x; kf[tl][5] = q1.y; kf[tl][6] = q1.z; kf[tl][7] = q1.w;
                }
            }
#pragma unroll
            for (int i = 0; i < 8; i++) {
                float w0 = wk_s[h + i], w1 = wk_s[512 + h + i];
                float w2 = wk_s[1024 + h + i], w3 = wk_s[1536 + h + i];
#pragma unroll
                for (int tl = 0; tl < 4; tl++) {
                    acc[tl][0] = fmaf(kf[tl][i], w0, acc[tl][0]);
                    acc[tl][1] = fmaf(kf[tl][i], w1, acc[tl][1]);
                    acc[tl][2] = fmaf(kf[tl][i], w2, acc[tl][2]);
                    acc[tl][3] = fmaf(kf[tl][i], w3, acc[tl][3]);
                }
            }
        }
#pragma unroll
        for (int tl = 0; tl < 4; tl++) {
            int t = tid + 256 * tl;
#pragma unroll
            for (int n = 0; n < 4; n++)
                sm[n][t] = (t < len) ? acc[tl][n] * SCALE_F : -1e30f;
        }
    }
    __syncthreads();

    // masked softmax per head (store exp, fold 1/sum later)
    for (int n = 0; n < 4; n++) {
        float m = -1e30f;
        for (int tl = 0; tl < 4; tl++) m = fmaxf(m, sm[n][tid + 256 * tl]);
        red[tid] = m; __syncthreads();
        for (int off = 128; off; off >>= 1) {
            if (tid < off) red[tid] = fmaxf(red[tid], red[tid + off]);
            __syncthreads();
        }
        m = red[0]; __syncthreads();
        float e = 0.0f;
        for (int tl = 0; tl < 4; tl++) {
            int t = tid + 256 * tl;
            float x = (t < len) ? __expf(sm[n][t] - m) : 0.0f;
            sm[n][t] = x; e += x;
        }
        red[tid] = e; __syncthreads();
        for (int off = 128; off; off >>= 1) {
            if (tid < off) red[tid] += red[tid + off];
            __syncthreads();
        }
        if (tid == 0) stat[n] = 1.0f / red[0];
        __syncthreads();
    }

    // av[b][n][h] = (1/sum) * sum_t exp_score * values[t,b,h]; thread owns h=2*tid, 2*tid+1
    {
        float a[4][2] = {};
        int h0 = 2 * tid;
        for (int t = 0; t < len; t++) {
            size_t base = ((size_t)t * 64 + b) * 512 + h0;
            float2 p;
            if (isb) p = bfpair(*(const u32*)(valB + base));
            else     p = *(const float2*)(valF + base);
            float s0 = sm[0][t], s1 = sm[1][t], s2 = sm[2][t], s3 = sm[3][t];
            a[0][0] = fmaf(s0, p.x, a[0][0]); a[0][1] = fmaf(s0, p.y, a[0][1]);
            a[1][0] = fmaf(s1, p.x, a[1][0]); a[1][1] = fmaf(s1, p.y, a[1][1]);
            a[2][0] = fmaf(s2, p.x, a[2][0]); a[2][1] = fmaf(s2, p.y, a[2][1]);
            a[3][0] = fmaf(s3, p.x, a[3][0]); a[3][1] = fmaf(s3, p.y, a[3][1]);
        }
#pragma unroll
        for (int n = 0; n < 4; n++) {
            av[((size_t)b * 4 + n) * 512 + h0]     = a[n][0] * stat[n];
            av[((size_t)b * 4 + n) * 512 + h0 + 1] = a[n][1] * stat[n];
        }
    }
}

__global__ __launch_bounds__(256) void las_head(const float* av, const u16* Wv, const u16* bv,
                                                float* head) {
    int idx = blockIdx.x * 256 + threadIdx.x;   // < 32768
    int b = idx >> 9, nd = idx & 511, n = nd >> 7;
    float acc = bfc(bv[nd]);
    const u32* wr = (const u32*)(Wv + (size_t)nd * 512);
    const float* ap = av + ((size_t)b * 4 + n) * 512;
    for (int h = 0; h < 512; h += 8) {
        uint4 wv = *(const uint4*)(wr + (h >> 1));
        float2 p;
        p = bfpair(wv.x); acc = fmaf(p.x, ap[h + 0], acc); acc = fmaf(p.y, ap[h + 1], acc);
        p = bfpair(wv.y); acc = fmaf(p.x, ap[h + 2], acc); acc = fmaf(p.y, ap[h + 3], acc);
        p = bfpair(wv.z); acc = fmaf(p.x, ap[h + 4], acc); acc = fmaf(p.y, ap[h + 5], acc);
        p = bfpair(wv.w); acc = fmaf(p.x, ap[h + 6], acc); acc = fmaf(p.y, ap[h + 7], acc);
    }
    head[idx] = acc;
}

__global__ __launch_bounds__(256) void las_ctx(const float* head, const u16* W_mh, const u16* b_mh,
                                               float* ctxT) {
    int idx = blockIdx.x * 256 + threadIdx.x;   // < 32768
    int b = idx >> 9, i = idx & 511;
    float acc = bfc(b_mh[i]);
    const u32* wr = (const u32*)(W_mh + (size_t)i * 512);
    const float* hp = head + (size_t)b * 512;
    for (int h = 0; h < 512; h += 8) {
        uint4 wv = *(const uint4*)(wr + (h >> 1));
        float2 p;
        p = bfpair(wv.x); acc = fmaf(p.x, hp[h + 0], acc); acc = fmaf(p.y, hp[h + 1], acc);
        p = bfpair(wv.y); acc = fmaf(p.x, hp[h + 2], acc); acc = fmaf(p.y, hp[h + 3], acc);
        p = bfpair(wv.z); acc = fmaf(p.x, hp[h + 4], acc); acc = fmaf(p.y, hp[h + 5], acc);
        p = bfpair(wv.w); acc = fmaf(p.x, hp[h + 6], acc); acc = fmaf(p.y, hp[h + 7], acc);
    }
    ctxT[(size_t)i * 64 + b] = acc;
}

__global__ __launch_bounds__(256) void las_embg(const u16* W_emb, const u16* Wih0, float* embg) {
    int idx = blockIdx.x * 256 + threadIdx.x;
    if (idx >= 4096 * 34) return;
    int row = idx / 34, v = idx - row * 34;
    const u32* wr = (const u32*)(Wih0 + (size_t)row * 1024);  // x-part: first 512 cols
    const u32* er = (const u32*)(W_emb + (size_t)v * 512);
    float acc = 0.0f;
    for (int h = 0; h < 512; h += 8) {
        uint4 wv = *(const uint4*)(wr + (h >> 1));
        uint4 ev = *(const uint4*)(er + (h >> 1));
        float2 a, c;
        a = bfpair(wv.x); c = bfpair(ev.x); acc = fmaf(a.x, c.x, acc); acc = fmaf(a.y, c.y, acc);
        a = bfpair(wv.y); c = bfpair(ev.y); acc = fmaf(a.x, c.x, acc); acc = fmaf(a.y, c.y, acc);
        a = bfpair(wv.z); c = bfpair(ev.z); acc = fmaf(a.x, c.x, acc); acc = fmaf(a.y, c.y, acc);
        a = bfpair(wv.w); c = bfpair(ev.w); acc = fmaf(a.x, c.x, acc); acc = fmaf(a.y, c.y, acc);
    }
    embg[idx] = acc;
}

__global__ __launch_bounds__(256) void las_ctxg(const float* ctxT, const u16* Wih0,
                                                const u16* bih0, const u16* bhh0, float* ctxg) {
    int lane = threadIdx.x & 63, w = threadIdx.x >> 6;
    int row = blockIdx.x * 4 + w;               // < 4096
    float acc = bfc(bih0[row]) + bfc(bhh0[row]);
    const u32* wr = (const u32*)(Wih0 + (size_t)row * 1024 + 512);  // context-part
    for (int h = 0; h < 512; h += 8) {
        float hv[8];
#pragma unroll
        for (int i = 0; i < 8; i++) hv[i] = ctxT[(size_t)(h + i) * 64 + lane];
        uint4 wv = *(const uint4*)(wr + (h >> 1));
        fma8(acc, wv, hv);
    }
    ctxg[(size_t)row * 64 + lane] = acc;
}

__global__ __launch_bounds__(256) void las_ctxp1(const float* ctxT, const u16* W_p1,
                                                 const u16* b_p1, float* ctxp1) {
    int lane = threadIdx.x & 63, w = threadIdx.x >> 6;
    int i = blockIdx.x * 4 + w;                 // < 512
    float acc = bfc(b_p1[i]);
    const u32* wr = (const u32*)(W_p1 + (size_t)i * 1024 + 512);
    for (int h = 0; h < 512; h += 8) {
        float hv[8];
#pragma unroll
        for (int k = 0; k < 8; k++) hv[k] = ctxT[(size_t)(h + k) * 64 + lane];
        uint4 wv = *(const uint4*)(wr + (h >> 1));
        fma8(acc, wv, hv);
    }
    ctxp1[(size_t)i * 64 + lane] = acc;
}

// ---------------- per-step kernels ----------------

__global__ __launch_bounds__(256) void las_l0(const int* labTt, const float* embg, const float* ctxg,
                                              const float* h0c, float* h0n, float* c0,
                                              const u16* Whh0) {
    int lane = threadIdx.x & 63, w = threadIdx.x >> 6;
    int j = blockIdx.x * 4 + w;                 // < 1024
    int vb = labTt[lane];
    float a0 = embg[(size_t)j * 34 + vb]          + ctxg[(size_t)j * 64 + lane];
    float a1 = embg[(size_t)(1024 + j) * 34 + vb] + ctxg[(size_t)(1024 + j) * 64 + lane];
    float a2 = embg[(size_t)(2048 + j) * 34 + vb] + ctxg[(size_t)(2048 + j) * 64 + lane];
    float a3 = embg[(size_t)(3072 + j) * 34 + vb] + ctxg[(size_t)(3072 + j) * 64 + lane];
    dot4(Whh0, j, 1024 + j, 2048 + j, 3072 + j, 1024, 1024, h0c, lane, a0, a1, a2, a3);
    int o = j * 64 + lane;
    float c = c0[o];
    float ig = sigf(a0), fg = sigf(a1), gg = tanh_(a2), og = sigf(a3);
    float c2 = fmaf(fg, c, ig * gg);
    c0[o] = c2;
    h0n[o] = og * tanh_(c2);
}

__global__ __launch_bounds__(256) void las_l1(const float* xT, const float* hc, float* hn, float* cT,
                                              const u16* Wih, const u16* Whh,
                                              const u16* bi, const u16* bh) {
    int lane = threadIdx.x & 63, w = threadIdx.x >> 6;
    int j = blockIdx.x * 4 + w;                 // < 1024
    float a0 = bfc(bi[j])        + bfc(bh[j]);
    float a1 = bfc(bi[1024 + j]) + bfc(bh[1024 + j]);
    float a2 = bfc(bi[2048 + j]) + bfc(bh[2048 + j]);
    float a3 = bfc(bi[3072 + j]) + bfc(bh[3072 + j]);
    dot4(Wih, j, 1024 + j, 2048 + j, 3072 + j, 1024, 1024, xT, lane, a0, a1, a2, a3);
    dot4(Whh, j, 1024 + j, 2048 + j, 3072 + j, 1024, 1024, hc, lane, a0, a1, a2, a3);
    int o = j * 64 + lane;
    float c = cT[o];
    float ig = sigf(a0), fg = sigf(a1), gg = tanh_(a2), og = sigf(a3);
    float c2 = fmaf(fg, c, ig * gg);
    cT[o] = c2;
    hn[o] = og * tanh_(c2);
}

__global__ __launch_bounds__(128) void las_l2(const float* xT, const float* hc, float* hn, float* cT,
                                              const u16* Wih, const u16* Whh,
                                              const u16* bi, const u16* bh) {
    int lane = threadIdx.x & 63, w = threadIdx.x >> 6;
    int j = blockIdx.x * 2 + w;                 // < 512
    float a0 = bfc(bi[j])        + bfc(bh[j]);
    float a1 = bfc(bi[512 + j])  + bfc(bh[512 + j]);
    float a2 = bfc(bi[1024 + j]) + bfc(bh[1024 + j]);
    float a3 = bfc(bi[1536 + j]) + bfc(bh[1536 + j]);
    dot4(Wih, j, 512 + j, 1024 + j, 1536 + j, 1024, 1024, xT, lane, a0, a1, a2, a3);
    dot4(Whh, j, 512 + j, 1024 + j, 1536 + j, 512, 512, hc, lane, a0, a1, a2, a3);
    int o = j * 64 + lane;
    float c = cT[o];
    float ig = sigf(a0), fg = sigf(a1), gg = tanh_(a2), og = sigf(a3);
    float c2 = fmaf(fg, c, ig * gg);
    cT[o] = c2;
    hn[o] = og * tanh_(c2);
}

__global__ __launch_bounds__(128) void las_p3a(const float* h2n, const float* ctxp1,
                                               const u16* W_p1, float* yT) {
    int lane = threadIdx.x & 63, w = threadIdx.x >> 6;
    int i = blockIdx.x * 2 + w;                 // < 512
    float acc = ctxp1[(size_t)i * 64 + lane];
    const u32* wr = (const u32*)(W_p1 + (size_t)i * 1024);  // h2-part: first 512 cols
#pragma unroll 2
    for (int k = 0; k < 512; k += 8) {
        float hv[8];
#pragma unroll
        for (int q = 0; q < 8; q++) hv[q] = h2n[(k + q) * 64 + lane];
        uint4 wv = *(const uint4*)(wr + (k >> 1));
        fma8(acc, wv, hv);
    }
    acc = acc > 0.0f ? acc : 0.01f * acc;       // leaky_relu
    yT[(size_t)i * 64 + lane] = acc;
}

__global__ __launch_bounds__(64) void las_p3b(const float* yT, const u16* W_emb, const u16* b_proj2,
                                              const int* flag, void* outp, int t) {
    int b = blockIdx.x;
    int v = threadIdx.x;                        // 64 lanes, v<34 active
    float acc = -1e30f;
    if (v < 34) {
        acc = bfc(b_proj2[v]);
        const u32* wr = (const u32*)(W_emb + (size_t)v * 512);
        for (int i = 0; i < 512; i += 8) {
            uint4 wv = *(const uint4*)(wr + (i >> 1));
            float y0 = yT[(i + 0) * 64 + b], y1 = yT[(i + 1) * 64 + b];
            float y2 = yT[(i + 2) * 64 + b], y3 = yT[(i + 3) * 64 + b];
            float y4 = yT[(i + 4) * 64 + b], y5 = yT[(i + 5) * 64 + b];
            float y6 = yT[(i + 6) * 64 + b], y7 = yT[(i + 7) * 64 + b];
            float2 p;
            p = bfpair(wv.x); acc = fmaf(p.x, y0, acc); acc = fmaf(p.y, y1, acc);
            p = bfpair(wv.y); acc = fmaf(p.x, y2, acc); acc = fmaf(p.y, y3, acc);
            p = bfpair(wv.z); acc = fmaf(p.x, y4, acc); acc = fmaf(p.y, y5, acc);
            p = bfpair(wv.w); acc = fmaf(p.x, y6, acc); acc = fmaf(p.y, y7, acc);
        }
    }
    float m = acc;
    for (int off = 32; off; off >>= 1) m = fmaxf(m, __shfl_xor(m, off, 64));
    float e = (v < 34) ? __expf(acc - m) : 0.0f;
    float s = e;
    for (int off = 32; off; off >>= 1) s += __shfl_xor(s, off, 64);
    if (v < 34) {
        float r = acc - m - __logf(s);
        size_t o = ((size_t)b * 255 + t) * 34 + v;
        if (flag[0]) ((u16*)outp)[o] = f2bf(r);
        else         ((float*)outp)[o] = r;
    }
}

// ---------------- failure instrumentation ----------------

__global__ __launch_bounds__(256) void las_nanscan(const void* outp, const int* flag, int* cnt, int n) {
    int g = blockIdx.x * 256 + threadIdx.x;
    if (g >= n) return;
    bool bad;
    if (flag[0]) {
        u16 v = ((const u16*)outp)[g];
        bad = ((v & 0x7F80u) == 0x7F80u);
    } else {
        float f = ((const float*)outp)[g];
        bad = !isfinite(f);
    }
    if (bad) atomicAdd(cnt, 1);
}

__global__ __launch_bounds__(64) void las_nansig(void* outp, const int* flag, const int* cnt) {
    if (threadIdx.x != 0) return;
    int c = cnt[0];
    if (c > 0) {
        int cc = c < 9999 ? c : 9999;
        float sig = 10000.0f * (float)(1 + flag[0]) + (float)cc;
        if (flag[0]) ((u16*)outp)[0] = f2bf(sig);
        else         ((float*)outp)[0] = sig;
    }
}

// ---------------- host ----------------

extern "C" void kernel_launch(void* const* d_in, const int* in_sizes, int n_in,
                              void* d_out, int out_size, void* d_ws, size_t ws_size,
                              hipStream_t stream) {
    const void* keys     = d_in[0];
    const void* values   = d_in[1];
    const int* label     = (const int*)d_in[2];
    const int* input_len = (const int*)d_in[4];

    float* F     = (float*)d_ws;
    float* q     = F + O_QUERY;
    float* nq    = F + O_NQ;
    float* wk    = F + O_WK;
    float* kb    = F + O_KB;
    int*   flag  = (int*)(F + O_FLAG);          // flag[0]=is_bf16, flag[1]=nan counter
    float* av    = F + O_AV;
    float* head  = F + O_HEAD;
    float* ctxT  = F + O_CTXT;
    float* embg  = F + O_EMBG;
    float* ctxg  = F + O_CTXG;
    float* ctxp1 = F + O_CTXP1;
    float* c0T   = F + O_C0T;
    float* c1T   = F + O_C1T;
    float* c2T   = F + O_C2T;
    float* yT    = F + O_YT;
    int*   labT  = (int*)(F + O_LABT);
    float* h0buf[2] = { F + O_H0T, F + O_H0T + 65536 };
    float* h1buf[2] = { F + O_H1T, F + O_H1T + 65536 };
    float* h2buf[2] = { F + O_H2T, F + O_H2T + 32768 };
    u16*   cw    = (u16*)d_ws + 2 * (size_t)O_CANON;

    // canonicalization descriptor: d_in[6..37] in order
    static const unsigned kLen[NSEG] = {
        17408, 34, 262144, 512, 262144, 512, 262144, 512, 262144, 512,
        262144, 512, 524288, 512, 4194304, 4194304, 4096, 4096, 1024, 1024,
        4194304, 4194304, 4096, 4096, 1024, 1024, 2097152, 1048576, 2048, 2048,
        512, 512
    };
    Cvt cv;
    const u16* cwp[NSEG];
    unsigned o = 0;
    for (int i = 0; i < NSEG; i++) {
        cv.src[i] = d_in[6 + i];
        cv.ofs[i] = o;
        cv.len[i] = kLen[i];
        cwp[i] = cw + o;
        o += (kLen[i] + 7u) & ~7u;
    }
    cv.ofs[NSEG] = o;

    const u16 *W_emb = cwp[0], *b_proj2 = cwp[1], *W_query = cwp[2], *b_query = cwp[3];
    const u16 *Wk = cwp[4], *bk = cwp[5], *Wq = cwp[6], *bq = cwp[7];
    const u16 *Wv = cwp[8], *bv = cwp[9], *W_mh = cwp[10], *b_mh = cwp[11];
    const u16 *W_p1 = cwp[12], *b_p1 = cwp[13], *Wih0 = cwp[14], *Whh0 = cwp[15];
    const u16 *bih0 = cwp[16], *bhh0 = cwp[17], *h00 = cwp[18], *c00 = cwp[19];
    const u16 *Wih1 = cwp[20], *Whh1 = cwp[21], *bih1 = cwp[22], *bhh1 = cwp[23];
    const u16 *h01 = cwp[24], *c01 = cwp[25], *Wih2 = cwp[26], *Whh2 = cwp[27];
    const u16 *bih2 = cwp[28], *bhh2 = cwp[29], *h02 = cwp[30], *c02 = cwp[31];
    (void)h01; (void)c01;

    // dtype detect + canonicalize to bf16
    las_detect<<<1, 256, 0, stream>>>((const u16*)d_in[8], flag);
    las_convert<<<4096, 256, 0, stream>>>(cv, flag, cw);

    // one-time setup
    las_init<<<256, 256, 0, stream>>>(h00, c00, cwp[24], cwp[25], h02, c02, label,
                                      h0buf[0], c0T, h1buf[0], c1T, h2buf[0], c2T, labT);
    las_query<<<2, 256, 0, stream>>>(h02, W_query, b_query, q);
    las_nq<<<2, 256, 0, stream>>>(q, Wq, bq, nq);
    las_wk<<<8, 256, 0, stream>>>(nq, Wk, bk, wk, kb);
    las_attn<<<64, 256, 0, stream>>>(keys, values, input_len, flag, wk, kb, av);
    las_head<<<128, 256, 0, stream>>>(av, Wv, bv, head);
    las_ctx<<<128, 256, 0, stream>>>(head, W_mh, b_mh, ctxT);
    las_embg<<<545, 256, 0, stream>>>(W_emb, Wih0, embg);
    las_ctxg<<<1024, 256, 0, stream>>>(ctxT, Wih0, bih0, bhh0, ctxg);
    las_ctxp1<<<128, 256, 0, stream>>>(ctxT, W_p1, b_p1, ctxp1);

    // 255 decode steps
    for (int t = 0; t < 255; t++) {
        int c = t & 1, n = c ^ 1;
        las_l0<<<256, 256, 0, stream>>>(labT + t * 64, embg, ctxg, h0buf[c], h0buf[n], c0T, Whh0);
        las_l1<<<256, 256, 0, stream>>>(h0buf[n], h1buf[c], h1buf[n], c1T, Wih1, Whh1, bih1, bhh1);
        las_l2<<<256, 128, 0, stream>>>(h1buf[n], h2buf[c], h2buf[n], c2T, Wih2, Whh2, bih2, bhh2);
        las_p3a<<<256, 128, 0, stream>>>(h2buf[n], ctxp1, W_p1, yT);
        las_p3b<<<64, 64, 0, stream>>>(yT, W_emb, b_proj2, flag, d_out, t);
    }

    // if anything non-finite leaked into the output, stamp a diagnostic signature
    int n_out = 64 * 255 * 34;
    las_nanscan<<<(n_out + 255) / 256, 256, 0, stream>>>(d_out, flag, flag + 1, n_out);
    las_nansig<<<1, 64, 0, stream>>>(d_out, flag, flag + 1);
}